// Round 1
// baseline (194.192 us; speedup 1.0000x reference)
//
#include <hip/hip_runtime.h>
#include <math.h>

// GLA: B=2, N=1024, D=1024, H=4, KD=512, VD=1024, DK=128, DV=256, LR=16
// Round 13: proj_mfma and out_mfma staging ported to global_load_lds width-16
// (m97 structure) with linear LDS + XOR both-sides swizzle (rule #21):
//   store: lane source col8 = (lane&7) ^ (lane>>3)   (inverse swizzle on global src)
//   read : chunk = (ks*4+qd) ^ (row&7)               (same involution on ds_read)
// proj retiled to 128x128 (4x4 frags/wave, grid 24x16=384); out keeps 64x128
// (grid 8x32=256 to fill CUs). K-accum order unchanged -> bit-identical output.
// Rest identical to round 12. 9 kernels. Workspace ~37 MB.

typedef __attribute__((ext_vector_type(4))) float vf4;
typedef __attribute__((ext_vector_type(4))) unsigned int vu4;
typedef __attribute__((ext_vector_type(8))) short short8;

#define DEVI static __device__ __forceinline__
DEVI vf4 vzero() { vf4 x = {0.f, 0.f, 0.f, 0.f}; return x; }

DEVI float bf2f(unsigned int u) {
  union { unsigned int i; float f; } c; c.i = u << 16; return c.f;
}
DEVI unsigned short f2bf(float f) {
  union { float f; unsigned int i; } c; c.f = f;
  unsigned int i = c.i;
  return (unsigned short)((i + 0x7fffu + ((i >> 16) & 1u)) >> 16);
}
DEVI void unpack8(vu4 r, float* f) {
  f[0] = bf2f(r.x & 0xffffu); f[1] = bf2f(r.x >> 16);
  f[2] = bf2f(r.y & 0xffffu); f[3] = bf2f(r.y >> 16);
  f[4] = bf2f(r.z & 0xffffu); f[5] = bf2f(r.z >> 16);
  f[6] = bf2f(r.w & 0xffffu); f[7] = bf2f(r.w >> 16);
}
DEVI vu4 pack8(const float* f) {
  vu4 o;
  o.x = (unsigned int)f2bf(f[0]) | ((unsigned int)f2bf(f[1]) << 16);
  o.y = (unsigned int)f2bf(f[2]) | ((unsigned int)f2bf(f[3]) << 16);
  o.z = (unsigned int)f2bf(f[4]) | ((unsigned int)f2bf(f[5]) << 16);
  o.w = (unsigned int)f2bf(f[6]) | ((unsigned int)f2bf(f[7]) << 16);
  return o;
}

// async global->LDS, 16B per lane, wave-uniform LDS base + lane*16 dest.
DEVI void gld16(const unsigned short* g, unsigned short* l) {
  __builtin_amdgcn_global_load_lds(
      (const __attribute__((address_space(1))) unsigned int*)g,
      (__attribute__((address_space(3))) unsigned int*)l,
      16, 0, 0);
}

// ---------------------------------------------------------------------------
// prep_k: ct<64 -> weight transpose+convert; ct>=64 -> x fp32->bf16.
// grid (96,16).
// ---------------------------------------------------------------------------
__global__ __launch_bounds__(256)
void prep_k(const float* __restrict__ Wq, const float* __restrict__ Wk,
            const float* __restrict__ Wv, const float* __restrict__ Wg,
            const float* __restrict__ Wo, const float* __restrict__ X,
            unsigned short* __restrict__ wqT, unsigned short* __restrict__ wkT,
            unsigned short* __restrict__ wvT, unsigned short* __restrict__ wgT,
            unsigned short* __restrict__ woT, unsigned short* __restrict__ xb) {
  __shared__ float T[64][65];
  const int ct = blockIdx.x, kt = blockIdx.y;
  const int t = threadIdx.x;
  const int r = t >> 2, s = t & 3;
  if (ct >= 64) {
    const int rt = ct - 64;
    const size_t base = (size_t)(rt * 64 + r) * 1024 + kt * 64 + s * 16;
    float f[16];
    *(vf4*)&f[0]  = *(const vf4*)(X + base);
    *(vf4*)&f[4]  = *(const vf4*)(X + base + 4);
    *(vf4*)&f[8]  = *(const vf4*)(X + base + 8);
    *(vf4*)&f[12] = *(const vf4*)(X + base + 12);
    *(vu4*)(xb + base) = pack8(f);
    *(vu4*)(xb + base + 8) = pack8(f + 8);
    return;
  }
  const float* W; unsigned short* O; int N; int cb;
  if (ct < 8)       { W = Wq; O = wqT; N = 512;  cb = ct; }
  else if (ct < 16) { W = Wk; O = wkT; N = 512;  cb = ct - 8; }
  else if (ct < 32) { W = Wv; O = wvT; N = 1024; cb = ct - 16; }
  else if (ct < 48) { W = Wg; O = wgT; N = 1024; cb = ct - 32; }
  else              { W = Wo; O = woT; N = 1024; cb = ct - 48; }
  const float* src = W + (size_t)(kt * 64 + r) * N + cb * 64 + s * 16;
#pragma unroll
  for (int u = 0; u < 4; ++u) {
    vf4 v4 = *(const vf4*)(src + u * 4);
    T[r][s * 16 + u * 4 + 0] = v4.x;
    T[r][s * 16 + u * 4 + 1] = v4.y;
    T[r][s * 16 + u * 4 + 2] = v4.z;
    T[r][s * 16 + u * 4 + 3] = v4.w;
  }
  __syncthreads();
  unsigned int pk[8];
#pragma unroll
  for (int u = 0; u < 8; ++u) {
    unsigned int lo = f2bf(T[s * 16 + 2 * u][r]);
    unsigned int hi = f2bf(T[s * 16 + 2 * u + 1][r]);
    pk[u] = lo | (hi << 16);
  }
  unsigned short* dst = O + (size_t)(cb * 64 + r) * 1024 + kt * 64 + s * 16;
  *(vu4*)dst = *(vu4*)&pk[0];
  *(vu4*)(dst + 8) = *(vu4*)&pk[4];
}

// ---------------------------------------------------------------------------
// MFMA projection: xb bf16 @ WT bf16 -> q,k,v,sg(silu) bf16.
// 128x128 tile, BK=64, global_load_lds staging, XOR-swizzled linear LDS.
// grid (24,16) = 384 blocks. LDS 32 KB.
// ---------------------------------------------------------------------------
__global__ __launch_bounds__(256)
void proj_mfma_k(const unsigned short* __restrict__ xb,
                 const unsigned short* __restrict__ wqT, const unsigned short* __restrict__ wkT,
                 const unsigned short* __restrict__ wvT, const unsigned short* __restrict__ wgT,
                 unsigned short* __restrict__ qb, unsigned short* __restrict__ kb,
                 unsigned short* __restrict__ vb, unsigned short* __restrict__ sgb) {
  __shared__ __align__(16) unsigned short As[128 * 64];
  __shared__ __align__(16) unsigned short Bs[128 * 64];
  const int t = threadIdx.x;
  const int m0 = blockIdx.y << 7;
  const int nt = blockIdx.x;
  const unsigned short* WT; int n0; int kind;
  if (nt < 4)       { WT = wqT; n0 = nt << 7;        kind = 0; }
  else if (nt < 8)  { WT = wkT; n0 = (nt - 4) << 7;  kind = 1; }
  else if (nt < 16) { WT = wvT; n0 = (nt - 8) << 7;  kind = 2; }
  else              { WT = wgT; n0 = (nt - 16) << 7; kind = 3; }

  const int w = t >> 6, lane = t & 63;
  const int wm = (w >> 1) << 6, wn = (w & 1) << 6;
  const int qd = lane >> 4, m = lane & 15;
  const int srow = lane >> 3;                   // 0..7 row-within-chunk
  const int scol = ((lane & 7) ^ srow) << 3;    // inverse-swizzled src col (elems)

  vf4 acc[4][4];
#pragma unroll
  for (int i = 0; i < 4; ++i)
#pragma unroll
    for (int j = 0; j < 4; ++j) acc[i][j] = vzero();

  for (int k0 = 0; k0 < 1024; k0 += 64) {
    __syncthreads();
    // stage 128x64 A + 128x64 B: 16 chunks each (1 KB = 8 rows), 4 per wave
#pragma unroll
    for (int cc = 0; cc < 4; ++cc) {
      const int c = (w << 2) + cc;
      const int row = (c << 3) + srow;
      gld16(xb + (size_t)(m0 + row) * 1024 + k0 + scol, (unsigned short*)As + (c << 9));
      gld16(WT + (size_t)(n0 + row) * 1024 + k0 + scol, (unsigned short*)Bs + (c << 9));
    }
    __syncthreads();
#pragma unroll
    for (int ks = 0; ks < 2; ++ks) {
      const int sw = (((ks << 2) + qd) ^ (m & 7)) << 3;  // swizzled read chunk
      short8 af[4], bf[4];
#pragma unroll
      for (int i = 0; i < 4; ++i)
        af[i] = *(const short8*)&As[(wm + i * 16 + m) * 64 + sw];
#pragma unroll
      for (int j = 0; j < 4; ++j)
        bf[j] = *(const short8*)&Bs[(wn + j * 16 + m) * 64 + sw];
#pragma unroll
      for (int i = 0; i < 4; ++i)
#pragma unroll
        for (int j = 0; j < 4; ++j)
          acc[i][j] = __builtin_amdgcn_mfma_f32_16x16x32_bf16(af[i], bf[j], acc[i][j], 0, 0, 0);
    }
  }
#pragma unroll
  for (int i = 0; i < 4; ++i) {
#pragma unroll
    for (int j = 0; j < 4; ++j) {
#pragma unroll
      for (int r = 0; r < 4; ++r) {
        const int grow = m0 + wm + i * 16 + qd * 4 + r;
        const int gcol = n0 + wn + j * 16 + m;
        float val = acc[i][j][r];
        if (kind == 0)      qb[(size_t)grow * 512 + gcol] = f2bf(val);
        else if (kind == 1) kb[(size_t)grow * 512 + gcol] = f2bf(val);
        else if (kind == 2) vb[(size_t)grow * 1024 + gcol] = f2bf(val);
        else {
          val = val / (1.f + expf(-val));
          sgb[(size_t)grow * 1024 + gcol] = f2bf(val);
        }
      }
    }
  }
}

// ---------------------------------------------------------------------------
// MFMA output GEMM: obuf_b bf16 @ woT -> d_out fp32.
// 64x128 tile, global_load_lds staging, XOR-swizzled linear LDS.
// grid (8,32) = 256 blocks.
// ---------------------------------------------------------------------------
__global__ __launch_bounds__(256)
void out_mfma_k(const unsigned short* __restrict__ Ab,
                const unsigned short* __restrict__ woT, float* __restrict__ Y) {
  __shared__ __align__(16) unsigned short As[64 * 64];
  __shared__ __align__(16) unsigned short Bs[128 * 64];
  const int t = threadIdx.x;
  const int m0 = blockIdx.y << 6;
  const int n0 = blockIdx.x << 7;
  const int w = t >> 6, lane = t & 63;
  const int wm = (w >> 1) * 32, wn = (w & 1) * 64;
  const int qd = lane >> 4, m = lane & 15;
  const int srow = lane >> 3;
  const int scol = ((lane & 7) ^ srow) << 3;

  vf4 acc[2][4];
#pragma unroll
  for (int i = 0; i < 2; ++i)
#pragma unroll
    for (int j = 0; j < 4; ++j) acc[i][j] = vzero();

  for (int k0 = 0; k0 < 1024; k0 += 64) {
    __syncthreads();
    // A: 64x64 = 8 chunks (2/wave); B: 128x64 = 16 chunks (4/wave)
#pragma unroll
    for (int cc = 0; cc < 2; ++cc) {
      const int c = (w << 1) + cc;
      const int row = (c << 3) + srow;
      gld16(Ab + (size_t)(m0 + row) * 1024 + k0 + scol, (unsigned short*)As + (c << 9));
    }
#pragma unroll
    for (int cc = 0; cc < 4; ++cc) {
      const int c = (w << 2) + cc;
      const int row = (c << 3) + srow;
      gld16(woT + (size_t)(n0 + row) * 1024 + k0 + scol, (unsigned short*)Bs + (c << 9));
    }
    __syncthreads();
#pragma unroll
    for (int ks = 0; ks < 2; ++ks) {
      const int sw = (((ks << 2) + qd) ^ (m & 7)) << 3;
      short8 af[2], bf[4];
#pragma unroll
      for (int i = 0; i < 2; ++i)
        af[i] = *(const short8*)&As[(wm + i * 16 + m) * 64 + sw];
#pragma unroll
      for (int j = 0; j < 4; ++j)
        bf[j] = *(const short8*)&Bs[(wn + j * 16 + m) * 64 + sw];
#pragma unroll
      for (int i = 0; i < 2; ++i)
#pragma unroll
        for (int j = 0; j < 4; ++j)
          acc[i][j] = __builtin_amdgcn_mfma_f32_16x16x32_bf16(af[i], bf[j], acc[i][j], 0, 0, 0);
    }
  }
#pragma unroll
  for (int i = 0; i < 2; ++i)
#pragma unroll
    for (int j = 0; j < 4; ++j)
#pragma unroll
      for (int r = 0; r < 4; ++r) {
        const int grow = m0 + wm + i * 16 + qd * 4 + r;
        const int gcol = n0 + wn + j * 16 + m;
        Y[(size_t)grow * 1024 + gcol] = acc[i][j][r];
      }
}

// ---------------------------------------------------------------------------
// xl = x @ Wgk1 [2048,16] fp32. One wave per row.
// ---------------------------------------------------------------------------
__global__ __launch_bounds__(64)
void lowrank_k(const float* __restrict__ X, const float* __restrict__ W1,
               float* __restrict__ xl) {
  const int row = blockIdx.x;
  const int t = threadIdx.x;
  float acc[16];
#pragma unroll
  for (int c2 = 0; c2 < 16; ++c2) acc[c2] = 0.f;
  const float* xp = X + (size_t)row * 1024 + t * 16;
  float xv[16];
#pragma unroll
  for (int u = 0; u < 4; ++u)
    *(vf4*)&xv[u * 4] = *(const vf4*)(xp + u * 4);
#pragma unroll
  for (int j = 0; j < 16; ++j) {
    const float* wp = W1 + (size_t)(t * 16 + j) * 16;
    float wv[16];
#pragma unroll
    for (int u = 0; u < 4; ++u)
      *(vf4*)&wv[u * 4] = *(const vf4*)(wp + u * 4);
#pragma unroll
    for (int c2 = 0; c2 < 16; ++c2) acc[c2] = fmaf(xv[j], wv[c2], acc[c2]);
  }
#pragma unroll
  for (int mm = 1; mm < 64; mm <<= 1) {
#pragma unroll
    for (int c2 = 0; c2 < 16; ++c2) acc[c2] += __shfl_xor(acc[c2], mm, 64);
  }
  if (t == 0) {
#pragma unroll
    for (int c2 = 0; c2 < 16; ++c2) xl[(size_t)row * 16 + c2] = acc[c2];
  }
}

// ---------------------------------------------------------------------------
// gate_scan v2-noLDS: one wave per (b, chunk, 16-kcol group); lane = row.
// grid 256 x 256.
// ---------------------------------------------------------------------------
__global__ __launch_bounds__(256)
void gate_scan_k(const float* __restrict__ xl, const float* __restrict__ W2,
                 const float* __restrict__ bias,
                 unsigned short* __restrict__ q, unsigned short* __restrict__ k,
                 float* __restrict__ ebtot) {
  const int t = threadIdx.x;
  const int w = t >> 6, lane = t & 63;
  const int wid = blockIdx.x * 4 + w;     // 0..1023
  const int kt = wid & 31;                // 16-col group
  const int c = (wid >> 5) & 15;
  const int b = wid >> 9;
  const int kbase = kt * 16;
  const size_t rowbase = (size_t)b * 1024 + c * 64;

  const float* xp = xl + (rowbase + lane) * 16;
  float xv[16];
#pragma unroll
  for (int u = 0; u < 4; ++u)
    *(vf4*)&xv[u * 4] = *(const vf4*)(xp + u * 4);

  const size_t a = (rowbase + lane) * 512 + kbase;
  vu4 qr0 = *(const vu4*)(q + a), qr1 = *(const vu4*)(q + a + 8);
  vu4 kr0 = *(const vu4*)(k + a), kr1 = *(const vu4*)(k + a + 8);
  float qf[16], kf[16];
  unpack8(qr0, qf); unpack8(qr1, qf + 8);
  unpack8(kr0, kf); unpack8(kr1, kf + 8);

  float gf[16];
#pragma unroll
  for (int cc = 0; cc < 16; ++cc) {
    const int col = kbase + cc;           // wave-uniform
    float z = bias[col];
#pragma unroll
    for (int j = 0; j < 16; ++j) z = fmaf(xv[j], W2[j * 512 + col], z);
    float ls = fminf(z, 0.f) - log1pf(expf(-fabsf(z)));
    float g = fmaxf(ls * (1.f / 16.f), -3.f);
#pragma unroll
    for (int d = 1; d < 64; d <<= 1) {
      float up = __shfl_up(g, d, 64);
      if (lane >= d) g += up;
    }
    qf[cc] *= expf(g);
    kf[cc] *= expf(fminf(-g, 80.f));
    gf[cc] = g;
  }
  *(vu4*)(q + a) = pack8(qf);
  *(vu4*)(q + a + 8) = pack8(qf + 8);
  *(vu4*)(k + a) = pack8(kf);
  *(vu4*)(k + a + 8) = pack8(kf + 8);
  if (lane == 63) {
    float* ep = ebtot + ((size_t)b * 16 + c) * 512 + kbase;
#pragma unroll
    for (int cc = 0; cc < 16; ++cc) ep[cc] = expf(gf[cc]);
  }
}

// ---------------------------------------------------------------------------
// Fused intra+kv, all-MFMA. grid (vh2, chunk16, bh8) = 256 blocks.
// ---------------------------------------------------------------------------
__global__ __launch_bounds__(256)
void intra_kv_k(const unsigned short* __restrict__ q16, const unsigned short* __restrict__ k16,
                const unsigned short* __restrict__ v, float* __restrict__ o,
                unsigned short* __restrict__ ST) {
  __shared__ __align__(16) unsigned short Qs[64 * 136];
  __shared__ __align__(16) unsigned short Ks[64 * 136];
  __shared__ __align__(16) unsigned short Kt[128 * 68];  // [k][j]
  __shared__ __align__(16) unsigned short Vt[128 * 68];  // [v-half][j]
  __shared__ __align__(16) unsigned short Asb[64 * 68];  // bf16 masked A
  const int t = threadIdx.x;
  const int vh = blockIdx.x, c = blockIdx.y, bh = blockIdx.z;
  const int b = bh >> 2, h = bh & 3;
  const size_t rowbase = (size_t)b * 1024 + c * 64;

#pragma unroll
  for (int u2 = 0; u2 < 4; ++u2) {
    const int id = t + (u2 << 8);
    const int row = id >> 4, kg = id & 15;
    vu4 rq = *(const vu4*)(q16 + (rowbase + row) * 512 + h * 128 + kg * 8);
    *(vu4*)&Qs[row * 136 + kg * 8] = rq;
    vu4 rk = *(const vu4*)(k16 + (rowbase + row) * 512 + h * 128 + kg * 8);
    *(vu4*)&Ks[row * 136 + kg * 8] = rk;
    const unsigned short* kp = (const unsigned short*)&rk;
#pragma unroll
    for (int u = 0; u < 8; ++u)
      Kt[(kg * 8 + u) * 68 + row] = kp[u];
    vu4 rv = *(const vu4*)(v + (rowbase + row) * 1024 + h * 256 + vh * 128 + kg * 8);
    const unsigned short* vp = (const unsigned short*)&rv;
#pragma unroll
    for (int u = 0; u < 8; ++u)
      Vt[(kg * 8 + u) * 68 + row] = vp[u];
  }
  __syncthreads();

  const int w = t >> 6, lane = t & 63;
  const int qd = lane >> 4, m = lane & 15;

  // phase 1: A = tril(Q K^T)
  {
    short8 af[4];
#pragma unroll
    for (int kf = 0; kf < 4; ++kf)
      af[kf] = *(const short8*)&Qs[(w * 16 + m) * 136 + kf * 32 + qd * 8];
    vf4 acc[4];
#pragma unroll
    for (int jt = 0; jt < 4; ++jt) acc[jt] = vzero();
#pragma unroll
    for (int jt = 0; jt < 4; ++jt)
#pragma unroll
      for (int kf = 0; kf < 4; ++kf) {
        short8 bfr = *(const short8*)&Ks[(jt * 16 + m) * 136 + kf * 32 + qd * 8];
        acc[jt] = __builtin_amdgcn_mfma_f32_16x16x32_bf16(af[kf], bfr, acc[jt], 0, 0, 0);
      }
#pragma unroll
    for (int jt = 0; jt < 4; ++jt)
#pragma unroll
      for (int r = 0; r < 4; ++r) {
        const int i = w * 16 + qd * 4 + r;
        const int j = jt * 16 + m;
        Asb[i * 68 + j] = f2bf((j <= i) ? acc[jt][r] : 0.f);
      }
  }
  __syncthreads();

  // phase 2: o_intra = A @ V
  {
    vf4 acc2[4][2];
#pragma unroll
    for (int mt = 0; mt < 4; ++mt) { acc2[mt][0] = vzero(); acc2[mt][1] = vzero(); }
#pragma unroll
    for (int kf = 0; kf < 2; ++kf) {
      short8 bf0 = *(const short8*)&Vt[(w * 32 + m) * 68 + kf * 32 + qd * 8];
      short8 bf1 = *(const short8*)&Vt[(w * 32 + 16 + m) * 68 + kf * 32 + qd * 8];
#pragma unroll
      for (int mt = 0; mt < 4; ++mt) {
        short8 af = *(const short8*)&Asb[(mt * 16 + m) * 68 + kf * 32 + qd * 8];
        acc2[mt][0] = __builtin_amdgcn_mfma_f32_16x16x32_bf16(af, bf0, acc2[mt][0], 0, 0, 0);
        acc2[mt][1] = __builtin_amdgcn_mfma_f32_16x16x32_bf16(af, bf1, acc2[mt][1], 0, 0, 0);
      }
    }
#pragma unroll
    for (int mt = 0; mt < 4; ++mt)
#pragma unroll
      for (int nt = 0; nt < 2; ++nt)
#pragma unroll
        for (int r = 0; r < 4; ++r) {
          const int i = mt * 16 + qd * 4 + r;
          const int vc = h * 256 + vh * 128 + w * 32 + nt * 16 + m;
          o[(rowbase + i) * 1024 + vc] = acc2[mt][nt][r];
        }
  }

  // phase 3: ST[v][k] = V^T @ K
  {
    short8 af3[2][2];
#pragma unroll
    for (int mt = 0; mt < 2; ++mt)
#pragma unroll
      for (int kf = 0; kf < 2; ++kf)
        af3[mt][kf] = *(const short8*)&Vt[(w * 32 + mt * 16 + m) * 68 + kf * 32 + qd * 8];
#pragma unroll
    for (int nt = 0; nt < 8; ++nt) {
      vf4 a0 = vzero(), a1 = vzero();
#pragma unroll
      for (int kf = 0; kf < 2; ++kf) {
        short8 bfr = *(const short8*)&Kt[(nt * 16 + m) * 68 + kf * 32 + qd * 8];
        a0 = __builtin_amdgcn_mfma_f32_16x16x32_bf16(af3[0][kf], bfr, a0, 0, 0, 0);
        a1 = __builtin_amdgcn_mfma_f32_16x16x32_bf16(af3[1][kf], bfr, a1, 0, 0, 0);
      }
      const size_t sbase = (size_t)(bh * 16 + c) * 256 + vh * 128 + w * 32;
#pragma unroll
      for (int r = 0; r < 4; ++r) {
        ST[(sbase + qd * 4 + r) * 128 + nt * 16 + m] = f2bf(a0[r]);
        ST[(sbase + 16 + qd * 4 + r) * 128 + nt * 16 + m] = f2bf(a1[r]);
      }
    }
  }
}

// ---------------------------------------------------------------------------
// State scan in place on bf16 ST[v][k]; fp32 carry; per-k decay vector.
// ---------------------------------------------------------------------------
__global__ __launch_bounds__(256)
void state_scan_k(unsigned short* __restrict__ ST, const float* __restrict__ ebtot) {
  const int idx = blockIdx.x * 256 + threadIdx.x;  // 0..32767
  const int kg = idx & 15;
  const int vv = (idx >> 4) & 255;
  const int bh = idx >> 12;
  const int b = bh >> 2, h = bh & 3;
  float s[8];
#pragma unroll
  for (int u = 0; u < 8; ++u) s[u] = 0.f;
  for (int c = 0; c < 16; ++c) {
    unsigned short* p = ST + ((size_t)(bh * 16 + c) * 256 + vv) * 128 + kg * 8;
    const float* ep = ebtot + ((size_t)b * 16 + c) * 512 + h * 128 + kg * 8;
    float e[8];
    *(vf4*)&e[0] = *(const vf4*)ep;
    *(vf4*)&e[4] = *(const vf4*)(ep + 4);
    float kv[8];
    unpack8(*(const vu4*)p, kv);
    *(vu4*)p = pack8(s);
#pragma unroll
    for (int u = 0; u < 8; ++u) s[u] = (s[u] + kv[u]) * e[u];
  }
}

// ---------------------------------------------------------------------------
// o += Q~ @ S_c via MFMA. grid (vt2, chunk16, bh8) = 256 blocks.
// ---------------------------------------------------------------------------
__global__ __launch_bounds__(256)
void o_inter_k(const unsigned short* __restrict__ q16, const unsigned short* __restrict__ ST,
               float* __restrict__ o) {
  __shared__ __align__(16) unsigned short Qs[64 * 136];
  __shared__ __align__(16) unsigned short Ss[128 * 136];
  const int t = threadIdx.x;
  const int vt = blockIdx.x, c = blockIdx.y, bh = blockIdx.z;
  const int b = bh >> 2, h = bh & 3;
  const size_t rowbase = (size_t)b * 1024 + c * 64;

#pragma unroll
  for (int u2 = 0; u2 < 4; ++u2) {
    const int id = t + (u2 << 8);
    const int row = id >> 4, kg = id & 15;
    *(vu4*)&Qs[row * 136 + kg * 8] =
        *(const vu4*)(q16 + (rowbase + row) * 512 + h * 128 + kg * 8);
  }
#pragma unroll
  for (int u2 = 0; u2 < 8; ++u2) {
    const int id = t + (u2 << 8);
    const int vrow = id >> 4, kg = id & 15;
    *(vu4*)&Ss[vrow * 136 + kg * 8] =
        *(const vu4*)(ST + ((size_t)(bh * 16 + c) * 256 + vt * 128 + vrow) * 128 + kg * 8);
  }
  __syncthreads();

  const int w = t >> 6, lane = t & 63;
  const int qd = lane >> 4, m = lane & 15;
  short8 af[4];
#pragma unroll
  for (int kf = 0; kf < 4; ++kf)
    af[kf] = *(const short8*)&Qs[(w * 16 + m) * 136 + kf * 32 + qd * 8];
#pragma unroll
  for (int nt = 0; nt < 8; ++nt) {
    vf4 acc = vzero();
#pragma unroll
    for (int kf = 0; kf < 4; ++kf) {
      short8 bfr = *(const short8*)&Ss[(nt * 16 + m) * 136 + kf * 32 + qd * 8];
      acc = __builtin_amdgcn_mfma_f32_16x16x32_bf16(af[kf], bfr, acc, 0, 0, 0);
    }
    float* base = o + (rowbase + w * 16 + qd * 4) * 1024 + h * 256 + vt * 128 + nt * 16 + m;
#pragma unroll
    for (int r = 0; r < 4; ++r)
      base[(size_t)r * 1024] += acc[r];
  }
}

// ---------------------------------------------------------------------------
// RMSNorm over DV=256 + silu-gate; obuf fp32 -> obuf_b bf16.
// ---------------------------------------------------------------------------
__global__ __launch_bounds__(256)
void norm_gate_k(const float* __restrict__ o, const float* __restrict__ rmsw,
                 const unsigned short* __restrict__ sg,
                 unsigned short* __restrict__ ob) {
  __shared__ float red[4];
  const int grp = blockIdx.x;
  const int row = grp >> 2, h = grp & 3;
  const int t = threadIdx.x;
  const size_t idx = (size_t)row * 1024 + h * 256 + t;
  const float val = o[idx];
  float ss = val * val;
#pragma unroll
  for (int mm = 1; mm < 64; mm <<= 1) ss += __shfl_xor(ss, mm, 64);
  if ((t & 63) == 0) red[t >> 6] = ss;
  __syncthreads();
  const float tot = red[0] + red[1] + red[2] + red[3];
  const float scale = rsqrtf(tot * (1.f / 256.f) + 1e-5f);
  ob[idx] = f2bf(val * scale * rmsw[t] * bf2f((unsigned int)sg[idx]));
}

// ---------------------------------------------------------------------------
extern "C" void kernel_launch(void* const* d_in, const int* in_sizes, int n_in,
                              void* d_out, int out_size, void* d_ws, size_t ws_size,
                              hipStream_t stream) {
  const float* x    = (const float*)d_in[0];
  const float* Wq   = (const float*)d_in[1];
  const float* Wk   = (const float*)d_in[2];
  const float* Wv   = (const float*)d_in[3];
  const float* Wg   = (const float*)d_in[4];
  const float* Wgk1 = (const float*)d_in[5];
  const float* Wgk2 = (const float*)d_in[6];
  const float* bgk2 = (const float*)d_in[7];
  const float* Wout = (const float*)d_in[8];
  const float* rmsw = (const float*)d_in[9];

  const size_t MB = 1u << 20;
  char* w = (char*)d_ws;
  unsigned short* qb16   = (unsigned short*)(w);           // [0,2) MB bf16
  unsigned short* kb16   = (unsigned short*)(w + 2 * MB);  // [2,4)
  unsigned short* vbuf   = (unsigned short*)(w + 4 * MB);  // [4,8)
  unsigned short* sgbuf  = (unsigned short*)(w + 8 * MB);  // [8,12)
  float*          obuf   = (float*)(w + 12 * MB);          // [12,20) fp32
  char*           sreg   = w + 20 * MB;                    // [20,28) multi-phase
  unsigned short* xb     = (unsigned short*)sreg;          //   phase 0: 4 MB
  unsigned short* STbuf  = (unsigned short*)sreg;          //   phase A: 8 MB [v][k]
  unsigned short* obuf_b = (unsigned short*)sreg;          //   phase B: 4 MB
  float*          xlbuf  = (float*)(w + 28 * MB);          // 128 KB
  float*          ebbuf  = (float*)(w + 28 * MB + 131072); // 64 KB
  unsigned short* wqT    = (unsigned short*)(w + 29 * MB); // 1 MB
  unsigned short* wkT    = (unsigned short*)(w + 30 * MB); // 1 MB
  unsigned short* wvT    = (unsigned short*)(w + 31 * MB); // 2 MB
  unsigned short* wgT    = (unsigned short*)(w + 33 * MB); // 2 MB
  unsigned short* woT    = (unsigned short*)(w + 35 * MB); // 2 MB

  prep_k<<<dim3(96, 16), 256, 0, stream>>>(Wq, Wk, Wv, Wg, Wout, x,
                                           wqT, wkT, wvT, wgT, woT, xb);
  lowrank_k<<<2048, 64, 0, stream>>>(x, Wgk1, xlbuf);
  proj_mfma_k<<<dim3(24, 16), 256, 0, stream>>>(xb, wqT, wkT, wvT, wgT, qb16, kb16, vbuf, sgbuf);
  gate_scan_k<<<256, 256, 0, stream>>>(xlbuf, Wgk2, bgk2, qb16, kb16, ebbuf);
  intra_kv_k<<<dim3(2, 16, 8), 256, 0, stream>>>(qb16, kb16, vbuf, obuf, STbuf);
  state_scan_k<<<128, 256, 0, stream>>>(STbuf, ebbuf);
  o_inter_k<<<dim3(2, 16, 8), 256, 0, stream>>>(qb16, STbuf, obuf);
  norm_gate_k<<<8192, 256, 0, stream>>>(obuf, rmsw, sgbuf, obuf_b);
  out_mfma_k<<<dim3(8, 32), 256, 0, stream>>>(obuf_b, woT, (float*)d_out);
}